// Round 9
// baseline (298.085 us; speedup 1.0000x reference)
//
#include <hip/hip_runtime.h>

#define N_NODES 40000
#define E_EDGES 640000
#define FDIM 128
#define RREL 4
#define NSEG (N_NODES * RREL)        // 160000
#define KBIG (RREL * FDIM)           // 512
#define KTOT (KBIG + FDIM)           // 640
#define SCAN_BLOCKS 625              // NSEG / 256
#define CSR_PAD (E_EDGES + 3 * NSEG) // 1120000 worst-case padded slots

typedef __attribute__((ext_vector_type(8))) short s16x8;
typedef __attribute__((ext_vector_type(4))) float f32x4;

__device__ __forceinline__ unsigned short f2bf(float f) {
    unsigned int b = __float_as_uint(f);
    b = (b + 0x7FFFu + ((b >> 16) & 1u)) >> 16;   // round-to-nearest-even
    return (unsigned short)b;
}
__device__ __forceinline__ float bflo(unsigned int v) { return __uint_as_float(v << 16); }
__device__ __forceinline__ float bfhi(unsigned int v) { return __uint_as_float(v & 0xFFFF0000u); }

// async global->LDS, 16B per lane; LDS dest must be wave-uniform base + lane*16
__device__ __forceinline__ void async_copy16(const void* gsrc, void* ldst) {
    __builtin_amdgcn_global_load_lds(
        (const __attribute__((address_space(1))) void*)gsrc,
        (__attribute__((address_space(3))) void*)ldst, 16, 0, 0);
}

__device__ __forceinline__ void acc8(float* s, uint4 v) {
    s[0] += bflo(v.x); s[1] += bfhi(v.x);
    s[2] += bflo(v.y); s[3] += bfhi(v.y);
    s[4] += bflo(v.z); s[5] += bfhi(v.z);
    s[6] += bflo(v.w); s[7] += bfhi(v.w);
}

// ---------------------------------------------------------------------------
// Fused setup: zero cnt+total | convert x->bf16 | convert+transpose weights |
//              fill csr with dummy idx | zero dummy rows of xb,h
// ---------------------------------------------------------------------------
#define SB_CNT 625
#define SB_CX  5000
#define SB_CW  640
#define SB_CF  4375   // CSR_PAD / 256

__global__ __launch_bounds__(256) void setup_kernel(
    const float* __restrict__ x,
    const float* __restrict__ w1, const float* __restrict__ r1,
    const float* __restrict__ w2, const float* __restrict__ r2,
    int* __restrict__ cnt, int* __restrict__ total,
    unsigned short* __restrict__ xb,
    unsigned short* __restrict__ wt1, unsigned short* __restrict__ wt2,
    int* __restrict__ csr, unsigned short* __restrict__ h) {
    const int bid = blockIdx.x;
    const int t = threadIdx.x;
    if (bid < SB_CNT) {
        cnt[bid * 256 + t] = 0;
        if (bid == 0 && t == 0) total[0] = 0;
    } else if (bid < SB_CNT + SB_CX) {
        int i = (bid - SB_CNT) * 256 + t;             // one float4 each
        float4 v = ((const float4*)x)[i];
        unsigned int p0 = (unsigned int)f2bf(v.x) | ((unsigned int)f2bf(v.y) << 16);
        unsigned int p1 = (unsigned int)f2bf(v.z) | ((unsigned int)f2bf(v.w) << 16);
        ((uint2*)xb)[i] = make_uint2(p0, p1);
    } else if (bid < SB_CNT + SB_CX + SB_CW) {
        int tl = (bid - SB_CNT - SB_CX) * 256 + t;    // 0 .. 2*128*640-1
        int layer = (tl >= FDIM * KTOT);
        if (layer) tl -= FDIM * KTOT;
        int oc = tl / KTOT;
        int k  = tl - oc * KTOT;
        const float* w = layer ? w2 : w1;
        const float* r = layer ? r2 : r1;
        float v;
        if (k < KBIG)
            v = w[((size_t)(k >> 7) * FDIM + (k & 127)) * FDIM + oc];
        else
            v = r[(size_t)(k - KBIG) * FDIM + oc];
        (layer ? wt2 : wt1)[(size_t)oc * KTOT + k] = f2bf(v);
    } else if (bid < SB_CNT + SB_CX + SB_CW + SB_CF) {
        int i = (bid - SB_CNT - SB_CX - SB_CW) * 256 + t;
        csr[i] = N_NODES;                             // dummy -> zero row
    } else {
        // zero the dummy rows xb[N] and h[N] (64 uints each)
        if (t < 64)        ((unsigned int*)(xb + (size_t)N_NODES * FDIM))[t] = 0;
        else if (t < 128)  ((unsigned int*)(h  + (size_t)N_NODES * FDIM))[t - 64] = 0;
    }
}

// ---------------------------------------------------------------------------
// histogram of segments (seg = dst*R + rel)
// ---------------------------------------------------------------------------
__global__ __launch_bounds__(256) void hist_kernel(const int* __restrict__ dst,
                                                   const int* __restrict__ et,
                                                   int* __restrict__ cnt) {
    int e = blockIdx.x * 256 + threadIdx.x;
    if (e >= E_EDGES) return;
    atomicAdd(&cnt[dst[e] * RREL + et[e]], 1);
}

// ---------------------------------------------------------------------------
// Single-kernel segment-base allocation: block-local scan of padded counts +
// one atomicAdd(total) per block for the block's base. Offsets are disjoint
// ranges (base order nondeterministic; aggregation result invariant).
// ---------------------------------------------------------------------------
__global__ __launch_bounds__(256) void alloc_scan(const int* __restrict__ cnt,
                                                  int* __restrict__ total,
                                                  int* __restrict__ offs,
                                                  int* __restrict__ cursor) {
    __shared__ int s[256];
    __shared__ int bb;
    const int t = threadIdx.x;
    const int g = blockIdx.x * 256 + t;
    const int pv = (cnt[g] + 3) & ~3;                 // padded count
    s[t] = pv;
    __syncthreads();
    for (int off = 1; off < 256; off <<= 1) {
        int u = (t >= off) ? s[t - off] : 0;
        __syncthreads();
        s[t] += u;
        __syncthreads();
    }
    if (t == 255) bb = atomicAdd(total, s[255]);
    __syncthreads();
    int ex = bb + s[t] - pv;                          // exclusive within block
    offs[g] = ex;
    cursor[g] = ex;
}

// ---------------------------------------------------------------------------
// scatter edge source-ids into CSR slots
// ---------------------------------------------------------------------------
__global__ __launch_bounds__(256) void build_kernel(const int* __restrict__ src,
                                                    const int* __restrict__ dst,
                                                    const int* __restrict__ et,
                                                    int* __restrict__ cursor,
                                                    int* __restrict__ csr_src) {
    int e = blockIdx.x * 256 + threadIdx.x;
    if (e >= E_EDGES) return;
    int seg = dst[e] * RREL + et[e];
    int pos = atomicAdd(&cursor[seg], 1);
    csr_src[pos] = src[e];
}

// ---------------------------------------------------------------------------
// Fused gather-GEMM:  out[n,:] = act( [mean_r(n)|xh(n)] @ wt^T + bias )
// Block = 64 rows x 128 oc, 4 waves (2x2). K chunks ks=0..4 (128 wide each).
// Chunks 0..3: each lane gather-means ITS OWN A-fragment in registers
//   (lane(lrow,lk8) owns rows {wr*32+lrow, wr*32+16+lrow}, k-slice lk8*8 of
//   every kt) -- no A LDS, no accb buffer. Chunk 4: direct fragment load.
// B chunk (32KB) staged async via global_load_lds; latency hides under gather.
// ---------------------------------------------------------------------------
template <int RELU, int OUT_BF16>
__global__ __launch_bounds__(256) void ggemm(
    const unsigned short* __restrict__ xb,    // [N+1][128] bf16 (gather source)
    const unsigned short* __restrict__ wt,    // [128][640] bf16
    const int* __restrict__ offs, const int* __restrict__ cnt_i,
    const int* __restrict__ csr,
    const float* __restrict__ bias,
    unsigned short* __restrict__ hout, float* __restrict__ fout) {
    __shared__ unsigned short sB[32 * 512];   // 128 oc x 128 k, fragment-linear

    const int tid = threadIdx.x;
    const int wid = tid >> 6, lane = tid & 63;
    const int lrow = lane & 15, lk8 = lane >> 4;
    const int row0 = blockIdx.x * 64;
    const int wr = wid >> 1, wc = wid & 1;

    f32x4 acc[2][4];
#pragma unroll
    for (int i = 0; i < 2; ++i)
#pragma unroll
        for (int j = 0; j < 4; ++j) acc[i][j] = (f32x4){0.f, 0.f, 0.f, 0.f};

    for (int ks = 0; ks < 5; ++ks) {
        // ---- stage B chunk: 32 frag-blocks over 4 waves = 8 async copies ----
#pragma unroll
        for (int it = 0; it < 8; ++it) {
            int d = wid * 8 + it;
            int nt = d >> 2, kt = d & 3;
            const unsigned short* gp =
                wt + (size_t)(nt * 16 + lrow) * KTOT + ks * 128 + kt * 32 + lk8 * 8;
            async_copy16(gp, &sB[d * 512]);
        }

        // ---- build A fragments in registers ----
        s16x8 afrag[2][4];
        if (ks < 4) {
#pragma unroll
            for (int i = 0; i < 2; ++i) {
                const int node = row0 + wr * 32 + i * 16 + lrow;
                const int seg = node * RREL + ks;
                const int base = offs[seg];
                const int c = cnt_i[seg];
                const int pc = (c + 3) & ~3;
                float s[4][8];
#pragma unroll
                for (int kt = 0; kt < 4; ++kt)
#pragma unroll
                    for (int j = 0; j < 8; ++j) s[kt][j] = 0.f;

                for (int p = base; p < base + pc; p += 4) {
                    int4 i4 = *(const int4*)(csr + p);
                    uint4 v[4][4];
#pragma unroll
                    for (int q = 0; q < 4; ++q) {
                        int idx = (q == 0) ? i4.x : (q == 1) ? i4.y : (q == 2) ? i4.z : i4.w;
                        const unsigned short* rp = xb + (size_t)idx * FDIM + lk8 * 8;
                        v[q][0] = *(const uint4*)(rp);
                        v[q][1] = *(const uint4*)(rp + 32);
                        v[q][2] = *(const uint4*)(rp + 64);
                        v[q][3] = *(const uint4*)(rp + 96);
                    }
#pragma unroll
                    for (int q = 0; q < 4; ++q)
#pragma unroll
                        for (int kt = 0; kt < 4; ++kt) acc8(s[kt], v[q][kt]);
                }
                const float rcp = 1.0f / (float)max(c, 1);
#pragma unroll
                for (int kt = 0; kt < 4; ++kt) {
                    s16x8 r;
#pragma unroll
                    for (int j = 0; j < 8; ++j) r[j] = (short)f2bf(s[kt][j] * rcp);
                    afrag[i][kt] = r;
                }
            }
        } else {
            // root chunk: direct bf16 fragment loads from own row
#pragma unroll
            for (int i = 0; i < 2; ++i) {
                const int node = row0 + wr * 32 + i * 16 + lrow;
                const unsigned short* rp = xb + (size_t)node * FDIM + lk8 * 8;
#pragma unroll
                for (int kt = 0; kt < 4; ++kt)
                    afrag[i][kt] = *(const s16x8*)(rp + kt * 32);
            }
        }

        __syncthreads();   // B chunk arrived (drains vmcnt) + all waves here

#pragma unroll
        for (int kt = 0; kt < 4; ++kt) {
            s16x8 b[4];
#pragma unroll
            for (int j = 0; j < 4; ++j)
                b[j] = *(const s16x8*)&sB[((wc * 4 + j) * 4 + kt) * 512 + lane * 8];
#pragma unroll
            for (int i = 0; i < 2; ++i)
#pragma unroll
                for (int j = 0; j < 4; ++j)
                    acc[i][j] = __builtin_amdgcn_mfma_f32_16x16x32_bf16(afrag[i][kt], b[j], acc[i][j], 0, 0, 0);
        }
        __syncthreads();   // sB reads done before next chunk overwrites
    }

    // epilogue: C/D layout col=lane&15, row=(lane>>4)*4+reg  [m89-verified]
    float bb[4];
#pragma unroll
    for (int j = 0; j < 4; ++j) bb[j] = bias[wc * 64 + j * 16 + lrow];
#pragma unroll
    for (int i = 0; i < 2; ++i)
#pragma unroll
        for (int j = 0; j < 4; ++j)
#pragma unroll
            for (int q = 0; q < 4; ++q) {
                int row = row0 + wr * 32 + i * 16 + lk8 * 4 + q;
                int col = wc * 64 + j * 16 + lrow;
                float v = acc[i][j][q] + bb[j];
                if (RELU) v = fmaxf(v, 0.f);
                if (OUT_BF16) hout[(size_t)row * FDIM + col] = f2bf(v);
                else          fout[(size_t)row * FDIM + col] = v;
            }
}

extern "C" void kernel_launch(void* const* d_in, const int* in_sizes, int n_in,
                              void* d_out, int out_size, void* d_ws, size_t ws_size,
                              hipStream_t stream) {
    const float* x     = (const float*)d_in[0];
    const float* w1    = (const float*)d_in[1];
    const float* root1 = (const float*)d_in[2];
    const float* b1    = (const float*)d_in[3];
    const float* w2    = (const float*)d_in[4];
    const float* root2 = (const float*)d_in[5];
    const float* b2    = (const float*)d_in[6];
    const int*   ei    = (const int*)d_in[7];   // [2, E]
    const int*   et    = (const int*)d_in[8];   // [E]
    float* out = (float*)d_out;

    const int* srcv = ei;
    const int* dstv = ei + E_EDGES;

    // ---- workspace layout ----
    size_t io = 0;
    int* cnt_i  = (int*)d_ws + io;  io += NSEG;
    int* offs   = (int*)d_ws + io;  io += NSEG;
    int* cursor = (int*)d_ws + io;  io += NSEG;
    int* csr    = (int*)d_ws + io;  io += CSR_PAD;
    int* total  = (int*)d_ws + io;  io += 1;
    io = (io + 63) & ~(size_t)63;                       // 256B-align
    unsigned short* us  = (unsigned short*)((int*)d_ws + io);
    size_t uo = 0;
    unsigned short* xb  = us + uo;  uo += (size_t)(N_NODES + 1) * FDIM;  // +dummy row
    unsigned short* wt1 = us + uo;  uo += (size_t)FDIM * KTOT;
    unsigned short* wt2 = us + uo;  uo += (size_t)FDIM * KTOT;
    unsigned short* h   = us + uo;  uo += (size_t)(N_NODES + 1) * FDIM;  // +dummy row

    const int eb = (E_EDGES + 255) / 256;      // 2500

    // ---- setup (zero cnt/total + converts + csr dummy-fill + zero dummy rows) ----
    setup_kernel<<<SB_CNT + SB_CX + SB_CW + SB_CF + 1, 256, 0, stream>>>(
        x, w1, root1, w2, root2, cnt_i, total, xb, wt1, wt2, csr, h);

    // ---- CSR build (once, reused by both layers) ----
    hist_kernel<<<eb, 256, 0, stream>>>(dstv, et, cnt_i);
    alloc_scan<<<SCAN_BLOCKS, 256, 0, stream>>>(cnt_i, total, offs, cursor);
    build_kernel<<<eb, 256, 0, stream>>>(srcv, dstv, et, cursor, csr);

    // ---- layer 1: h = relu(gatherGEMM(xb)) ----
    ggemm<1, 1><<<N_NODES / 64, 256, 0, stream>>>(
        xb, wt1, offs, cnt_i, csr, b1, h, nullptr);

    // ---- layer 2: out = gatherGEMM(h) ----
    ggemm<0, 0><<<N_NODES / 64, 256, 0, stream>>>(
        h, wt2, offs, cnt_i, csr, b2, nullptr, out);
}